// Round 6
// baseline (332.419 us; speedup 1.0000x reference)
//
#include <hip/hip_runtime.h>
#include <math.h>

// Problem constants (B, C, H, W) = (32, 10, 192, 320), fp32.
constexpr int B_ = 32, C_ = 10, H_ = 192, W_ = 320;
constexpr int HW_  = H_ * W_;        // 61440 (512 | HW_ -> no b-crossing per block)
constexpr int CHW_ = C_ * HW_;       // 614400
constexpr int NPTS = B_ * HW_;       // 1966080 spatial points
constexpr int PPT  = 2;              // points per thread (float2 loads) -- R0 proven shape
constexpr int TPB  = 256;
constexpr int NTHR = NPTS / PPT;     // 983040
constexpr int NBLK = NTHR / TPB;     // 3840 blocks, exact cover

// Partial-sum slots, ws[slot * NBLK + blk]; counter at ws + NACC*NBLK.
// 0: nv  1: num_pos
// 2: sum pos*(g0-r0)^2*log(safe+EPS)            (pos_term = -this)
// 3: sum neg*r0^2*log(1+EPS-safe)*(1-g0)^4      (neg_term = -this)
// 4: P  = 0.5*s_pos + 0.5*s_const + 0.1*s_h     (-> P/nv)
// 5: V1 = 0.05*s_len1 + 0.5*s_trig1             (-> V1/nv)
// 6: V2 = 0.05*s_len2 + 0.5*s_trig2             (-> V2/nv)
// loss = focal + (P + min(V1,V2)) / nv
#define NACC 7

typedef float f32x2 __attribute__((ext_vector_type(2)));

__device__ __forceinline__ float sl1f(float d) {
    float ad = fabsf(d);
    return ad < 1.0f ? 0.5f * d * d : ad - 0.5f;
}

// Round-9 design. Evidence chain: R0 (MLP~2-3, 19 waves/CU), R3 (verified
// 20 loads in flight, LDS-staged), R5 (verified loop-carried pipeline) ALL
// deliver 4.3 B/cyc/CU -> per-CU fill-path service cap (~30-70 outstanding
// lines tracked regardless of software queue depth). Two final levers:
// (1) NON-TEMPORAL loads: half our traffic is L3-hit (FETCH 79/157 MB).
//     If the L3-hit path is the limiter, nt (fills straight from HBM,
//     6.3 TB/s headroom) wins; if the per-CU cap is the limiter, time is
//     unchanged and FETCH_SIZE ~157MB is the closing signature -> roofline.
// (2) FUSED last-block reduce: kills the 2nd dispatch + its ramp.
//     Writer: thread0 stores 7 partials, __threadfence (release, wbl2),
//     atomicAdd (device-scope per m20). Last block: __threadfence
//     (acquire, inv), then reduces all 7*3840 partials. Counter zeroed by
//     hipMemsetAsync in kernel_launch (graph-capture-legal).
__global__ __launch_bounds__(TPB) void loss_fused(
    const float* __restrict__ re, const float* __restrict__ gt,
    float* __restrict__ ws, unsigned int* __restrict__ cnt,
    float* __restrict__ out)
{
    const int tid = blockIdx.x * TPB + threadIdx.x;
    const int p = tid * PPT;
    const int b = p / HW_;           // no b-crossing (PPT*TPB=512 divides HW_)
    const int s = p - b * HW_;
    const float* rp = re + (size_t)b * CHW_ + s;
    const float* gp = gt + (size_t)b * CHW_ + s;

    // 20 coalesced dwordx2 loads, non-temporal (no L1/L2/L3 allocation).
    f32x2 R[10], G[10];
#pragma unroll
    for (int c = 0; c < 10; ++c) {
        R[c] = __builtin_nontemporal_load((const f32x2*)(rp + c * HW_));
        G[c] = __builtin_nontemporal_load((const f32x2*)(gp + c * HW_));
    }

    float acc[NACC];
#pragma unroll
    for (int i = 0; i < NACC; ++i) acc[i] = 0.0f;

#pragma unroll
    for (int j = 0; j < PPT; ++j) {
        const float g = G[0][j], r = R[0][j];
        const float m = (g == 1.0f) ? 1.0f : 0.0f;
        acc[0] += m;
        const float pos = (g >= 0.1f) ? 1.0f : 0.0f;
        const float neg = ((g >= 0.0f) && (g < 0.1f)) ? 1.0f : 0.0f;
        acc[1] += pos;
        const float safe = fminf(fmaxf(r, 1e-6f), 1.0f - 1e-6f);
        // pos and neg mutually exclusive -> one logf with selected argument.
        const float larg = (pos != 0.0f) ? (safe + 6e-8f)
                                         : (1.0f + 6e-8f - safe);
        const float lg = logf(larg);
        const float d0 = g - r;
        acc[2] += pos * (d0 * d0) * lg;
        const float omg = 1.0f - g;
        const float omg2 = omg * omg;
        acc[3] += neg * (r * r) * (omg2 * omg2) * lg;

        const float r1 = R[1][j], r2 = R[2][j], r3 = R[3][j], r4v = R[4][j];
        const float r5 = R[5][j], r6 = R[6][j], r7 = R[7][j], r8 = R[8][j],
                    r9 = R[9][j];
        const float g1 = G[1][j], g2 = G[2][j], g3 = G[3][j], g4v = G[4][j];
        const float g5 = G[5][j], g6 = G[6][j], g7 = G[7][j], g8 = G[8][j],
                    g9 = G[9][j];

        // P: pos(0.5) + const(0.5) + height(0.1), all later /nv
        const float sp = sl1f(r1 - g1) + sl1f(r2 - g2);
        const float c1 = 1.0f - r5 * r5 - r4v * r4v;
        const float c2 = 1.0f - r8 * r8 - r7 * r7;
        const float sc = c1 * c1 + c2 * c2;
        const float sh = sl1f(r9 - g9);
        acc[4] += m * (0.5f * sp + 0.5f * sc + 0.1f * sh);

        // V1: 0.05*len1 + 0.5*trig1
        const float d44 = r4v - g4v, d77 = r7 - g7;
        const float d55 = r5 - g5,  d88 = r8 - g8;
        const float t1 = d44 * d44 + d77 * d77 + d55 * d55 + d88 * d88;
        const float l1 = sl1f(r3 - g3) + sl1f(r6 - g6);
        acc[5] += m * (0.05f * l1 + 0.5f * t1);

        // V2: 0.05*len2 + 0.5*trig2
        const float d47 = r4v - g7, d74 = r7 - g4v;
        const float d58 = r5 - g8,  d85 = r8 - g5;
        const float t2 = d47 * d47 + d74 * d74 + d58 * d58 + d85 * d85;
        const float l2 = sl1f(r3 - g6) + sl1f(r6 - g3);
        acc[6] += m * (0.05f * l2 + 0.5f * t2);
    }

    // block reduction: wave shuffle (64 lanes) -> LDS (4 waves)
    __shared__ float smem[NACC][4];
    const int lane = threadIdx.x & 63;
    const int wid  = threadIdx.x >> 6;
#pragma unroll
    for (int i = 0; i < NACC; ++i) {
        float v = acc[i];
#pragma unroll
        for (int off = 32; off > 0; off >>= 1) v += __shfl_down(v, off, 64);
        if (lane == 0) smem[i][wid] = v;
    }
    __syncthreads();

    // thread 0 stores ALL 7 partials (so one thread's release fence orders
    // them all), then signals completion.
    __shared__ int isLast;
    if (threadIdx.x == 0) {
#pragma unroll
        for (int i = 0; i < NACC; ++i)
            ws[i * NBLK + blockIdx.x] =
                smem[i][0] + smem[i][1] + smem[i][2] + smem[i][3];
        __threadfence();                                   // release (wbl2)
        isLast = (atomicAdd(cnt, 1u) == (unsigned)(NBLK - 1));
    }
    __syncthreads();
    if (!isLast) return;

    // ---- last block only: final reduction of 7 x 3840 partials ----
    __threadfence();                                       // acquire (inv)
    float a2[NACC];
#pragma unroll
    for (int i = 0; i < NACC; ++i) a2[i] = 0.0f;
#pragma unroll
    for (int k = 0; k < NBLK / TPB; ++k) {                 // 15 iterations
        const int idx = threadIdx.x + k * TPB;
#pragma unroll
        for (int i = 0; i < NACC; ++i)
            a2[i] += ws[i * NBLK + idx];
    }
#pragma unroll
    for (int i = 0; i < NACC; ++i) {
        float v = a2[i];
#pragma unroll
        for (int off = 32; off > 0; off >>= 1) v += __shfl_down(v, off, 64);
        if (lane == 0) smem[i][wid] = v;
    }
    __syncthreads();

    if (threadIdx.x == 0) {
        float slot[NACC];
#pragma unroll
        for (int i = 0; i < NACC; ++i)
            slot[i] = smem[i][0] + smem[i][1] + smem[i][2] + smem[i][3];
        const float nv    = slot[0];
        const float npos  = slot[1];
        const float pterm = -slot[2];
        const float nterm = -slot[3];
        const float focal = (npos == 0.0f) ? nterm : (pterm + nterm) / npos;
        out[0] = focal + (slot[4] + fminf(slot[5], slot[6])) / nv;
    }
}

extern "C" void kernel_launch(void* const* d_in, const int* in_sizes, int n_in,
                              void* d_out, int out_size, void* d_ws, size_t ws_size,
                              hipStream_t stream)
{
    const float* re = (const float*)d_in[0];
    const float* gt = (const float*)d_in[1];
    float* ws  = (float*)d_ws;
    unsigned int* cnt = (unsigned int*)(ws + NACC * NBLK);
    float* out = (float*)d_out;

    hipMemsetAsync(cnt, 0, sizeof(unsigned int), stream);
    loss_fused<<<NBLK, TPB, 0, stream>>>(re, gt, ws, cnt, out);
}